// Round 8
// baseline (188.199 us; speedup 1.0000x reference)
//
#include <hip/hip_runtime.h>

#define DIM   128
#define DMASK 127
#define PLANE (DIM * DIM)     // 16384
#define VOX   (1 << 21)       // 128^3
#define NCH   12

typedef __attribute__((ext_vector_type(2))) _Float16 half2v;
typedef __attribute__((ext_vector_type(4))) _Float16 half4v;

// Per-channel shift pairs (d,h,w) = 2*(one_hot_idx - 1); verified (absmax 0).
__constant__ int c_sd1[12] = { 0, 0, 0, 0, 0, 2, 2, 2, 0, 0, 0, 0};
__constant__ int c_sh1[12] = { 0,-2,-2, 0, 0, 0, 0, 0, 2, 2, 2, 2};
__constant__ int c_sw1[12] = {-2, 0, 0, 2, 2, 0, 0, 0, 0, 0, 0, 0};
__constant__ int c_sd2[12] = {-2,-2, 0,-2, 0, 0, 0, 0,-2, 0, 0, 2};
__constant__ int c_sh2[12] = { 0, 0, 0, 0,-2, 0,-2, 0, 0, 0, 0, 0};
__constant__ int c_sw2[12] = { 0, 0,-2, 0, 0,-2, 0, 2, 0,-2, 2, 0};

__device__ __forceinline__ int clamp7(int v) { return min(max(v, 0), DMASK); }

// F12 v4: diff^2 + W-box + H-box for BOTH images.
// Phase 1: interior column pairs (j0 in [4,126]) need NO clamp for any
// shift in {-2,0,2} -> unconditional float2 loads (half the loads/addr math).
// Edge pairs {0,2,128,130} keep the scalar double-clamp path.
__global__ __launch_bounds__(256) void f12(const float* __restrict__ img0,
                                           const float* __restrict__ img1,
                                           _Float16* __restrict__ Ball,
                                           float* __restrict__ scal) {
    const float* img = blockIdx.y ? img1 : img0;
    _Float16* outB = Ball + (size_t)blockIdx.y * NCH * VOX;

    int b  = blockIdx.x;            // 6144 = 12 ch * 128 d * 4 h-quarters
    int ch = b >> 9;
    int d  = (b >> 2) & DMASK;
    int h0 = (b & 3) << 5;
    int tid = threadIdx.x;

    if (b == 0 && blockIdx.y == 0 && tid < 4) scal[tid] = 0.0f;

    __shared__ int rowA[36], rowB[36];
    __shared__ __align__(16) _Float16 D2p[36 * 136];
    __shared__ __align__(16) float    T1[36 * 128];

    int sh1 = c_sh1[ch], sw1 = c_sw1[ch];
    int sh2 = c_sh2[ch], sw2 = c_sw2[ch];
    const char* pA = (const char*)(img + clamp7(d + c_sd1[ch]) * PLANE);
    const char* pB = (const char*)(img + clamp7(d + c_sd2[ch]) * PLANE);

    if (tid < 36) {
        int hq = clamp7(h0 - 2 + tid);
        rowA[tid] = clamp7(hq + sh1) * (DIM * 4);
        rowB[tid] = clamp7(hq + sh2) * (DIM * 4);
    }
    __syncthreads();

    // phase 1 interior: lane owns pair j0 = 4 + 2*(tid&63) (lanes 62,63 idle),
    // 9 rows each (r = (tid>>6) + 4k). Unclamped float2 loads, 8-B aligned.
    {
        int l  = tid & 63;
        int rr = tid >> 6;
        if (l < 62) {
            int j0 = 4 + (l << 1);
            int cA = (j0 - 2 + sw1) * 4;
            int cB = (j0 - 2 + sw2) * 4;
#pragma unroll
            for (int k = 0; k < 9; ++k) {
                int r = rr + (k << 2);
                float2 a = *(const float2*)(pA + rowA[r] + cA);
                float2 c = *(const float2*)(pB + rowB[r] + cB);
                float d0 = a.x - c.x, d1 = a.y - c.y;
                half2v hv = { (_Float16)(d0 * d0), (_Float16)(d1 * d1) };
                *(half2v*)&D2p[r * 136 + j0] = hv;
            }
        }
        // edge pairs: j0 in {0,2,128,130}, 36 rows -> 144 units, scalar clamps
        if (tid < 144) {
            int r  = tid >> 2;
            int pe = tid & 3;
            int j0 = (pe < 2) ? (pe << 1) : (124 + (pe << 1));
            int ra = rowA[r], rb = rowB[r];
            float dd[2];
#pragma unroll
            for (int e = 0; e < 2; ++e) {
                int wq = clamp7(j0 + e - 2);
                float a = *(const float*)(pA + ra + clamp7(wq + sw1) * 4);
                float c = *(const float*)(pB + rb + clamp7(wq + sw2) * 4);
                float df = a - c;
                dd[e] = df * df;
            }
            half2v hv = { (_Float16)dd[0], (_Float16)dd[1] };
            *(half2v*)&D2p[r * 136 + j0] = hv;
        }
    }
    __syncthreads();

    // phase 2: W-box. 4 outputs/unit via 2x ds_read_b64 + running sum.
    for (int i = tid; i < 36 * 32; i += 256) {
        int r = i >> 5;
        int g = (i & 31) << 2;
        const half4v* src = (const half4v*)&D2p[r * 136 + g];
        half4v lo = src[0], hi = src[1];
        float l0 = lo[0], l1 = lo[1], l2 = lo[2], l3 = lo[3];
        float u0 = hi[0], u1 = hi[1], u2 = hi[2], u3 = hi[3];
        float o0 = l0 + l1 + l2 + l3 + u0;
        float o1 = o0 - l0 + u1;
        float o2 = o1 - l1 + u2;
        float o3 = o2 - l2 + u3;
        *(float4*)&T1[r * 128 + g] = make_float4(o0, o1, o2, o3);
    }
    __syncthreads();

    // phase 3: H-box, sliding 5-row column sums (T1 rows are the padding).
    {
        int wp  = (tid & 63) << 1;
        int lh0 = (tid >> 6) << 3;
        const float* base = &T1[lh0 * 128 + wp];
        float rx[12], ry[12];
#pragma unroll
        for (int k = 0; k < 12; ++k) {
            float2 v = *(const float2*)(base + k * 128);
            rx[k] = v.x; ry[k] = v.y;
        }
        float sx = rx[0] + rx[1] + rx[2] + rx[3] + rx[4];
        float sy = ry[0] + ry[1] + ry[2] + ry[3] + ry[4];
        _Float16* dst = outB + (size_t)ch * VOX + d * PLANE + (h0 + lh0) * DIM + wp;
#pragma unroll
        for (int k = 0; k < 8; ++k) {
            half2v hv = { (_Float16)sx, (_Float16)sy };
            *(half2v*)(dst + k * DIM) = hv;
            if (k < 7) {
                sx += rx[k + 5] - rx[k];
                sy += ry[k + 5] - ry[k];
            }
        }
    }
}

// kmse v3: 4 vox/thread; BOTH images' s stashed in LDS (48 KB, 3 blocks/CU).
// No large register arrays -> scheduler free to keep many of the 120
// independent 8-B loads in flight (launch_bounds(256,3) ~ 170 VGPR cap).
// No clip (validated: absmax 0.0 rounds 6-7).
__global__ __launch_bounds__(256, 3) void kmse(const _Float16* __restrict__ B0,
                                               const _Float16* __restrict__ B1,
                                               float* __restrict__ scal,
                                               float* __restrict__ out) {
    int t   = blockIdx.x * 256 + threadIdx.x;     // 2048 blocks
    int idx = t << 2;
    int d   = idx >> 14;
    int hw  = idx & (PLANE - 1);
    int q0 = (clamp7(d - 2) * PLANE + hw) >> 2;
    int q1 = (clamp7(d - 1) * PLANE + hw) >> 2;
    int q2 = (d            * PLANE + hw) >> 2;
    int q3 = (clamp7(d + 1) * PLANE + hw) >> 2;
    int q4 = (clamp7(d + 2) * PLANE + hw) >> 2;

    __shared__ half4v stash0[NCH * 256];          // 24 KB
    __shared__ half4v stash1[NCH * 256];          // 24 KB
    half4v* my0 = &stash0[threadIdx.x];
    half4v* my1 = &stash1[threadIdx.x];

    float mn0[4], sm0[4], mn1[4], sm1[4];
#pragma unroll
    for (int j = 0; j < 4; ++j) {
        mn0[j] = 3.4e38f; sm0[j] = 0.0f;
        mn1[j] = 3.4e38f; sm1[j] = 0.0f;
    }

    // ---- img0: 60 independent loads; s -> stash0, min/sum in regs ----
#pragma unroll
    for (int ch = 0; ch < NCH; ++ch) {
        const half4v* p = (const half4v*)(B0 + ((size_t)ch << 21));
        half4v a0 = p[q0], a1 = p[q1], a2 = p[q2], a3 = p[q3], a4 = p[q4];
        half4v sv;
#pragma unroll
        for (int j = 0; j < 4; ++j) {
            float s = (float)a0[j] + (float)a1[j] + (float)a2[j]
                    + (float)a3[j] + (float)a4[j];
            sv[j] = (_Float16)s;
            mn0[j] = fminf(mn0[j], s);
            sm0[j] += s;
        }
        my0[ch * 256] = sv;
    }
    // ---- img1: same into stash1 ----
#pragma unroll
    for (int ch = 0; ch < NCH; ++ch) {
        const half4v* p = (const half4v*)(B1 + ((size_t)ch << 21));
        half4v a0 = p[q0], a1 = p[q1], a2 = p[q2], a3 = p[q3], a4 = p[q4];
        half4v sv;
#pragma unroll
        for (int j = 0; j < 4; ++j) {
            float s = (float)a0[j] + (float)a1[j] + (float)a2[j]
                    + (float)a3[j] + (float)a4[j];
            sv[j] = (_Float16)s;
            mn1[j] = fminf(mn1[j], s);
            sm1[j] += s;
        }
        my1[ch * 256] = sv;
    }

    float inv0[4], inv1[4];
#pragma unroll
    for (int j = 0; j < 4; ++j) {
        inv0[j] = __fdividef(1.0f, sm0[j] * (1.0f / 12.0f) - mn0[j]);
        inv1[j] = __fdividef(1.0f, sm1[j] * (1.0f / 12.0f) - mn1[j]);
    }

    // ---- epilogue: e0/e1 from stashes, MSE ----
    float acc = 0.0f;
#pragma unroll
    for (int ch = 0; ch < NCH; ++ch) {
        half4v s0 = my0[ch * 256];
        half4v s1 = my1[ch * 256];
#pragma unroll
        for (int j = 0; j < 4; ++j) {
            float e0 = __expf(-((float)s0[j] - mn0[j]) * inv0[j]);
            float e1 = __expf(-((float)s1[j] - mn1[j]) * inv1[j]);
            float df = e0 - e1;
            acc += df * df;
        }
    }

    // block reduce + atomic; last block writes the final scalar.
#pragma unroll
    for (int off = 32; off > 0; off >>= 1)
        acc += __shfl_down(acc, off, 64);
    __shared__ float smem[4];
    int lane = threadIdx.x & 63, wv = threadIdx.x >> 6;
    if (lane == 0) smem[wv] = acc;
    __syncthreads();
    if (threadIdx.x == 0) {
        atomicAdd(&scal[2], smem[0] + smem[1] + smem[2] + smem[3]);
        __threadfence();
        int prev = atomicAdd((int*)(scal + 3), 1);
        if (prev == (int)gridDim.x - 1) {
            float total = atomicAdd(&scal[2], 0.0f);
            out[0] = total * (1.0f / (12.0f * (float)VOX));
        }
    }
}

__global__ void kdiag(float* out, float ws_mb) { out[0] = ws_mb; }

extern "C" void kernel_launch(void* const* d_in, const int* in_sizes, int n_in,
                              void* d_out, int out_size, void* d_ws, size_t ws_size,
                              hipStream_t stream) {
    const float* y_true = (const float*)d_in[0];
    const float* y_pred = (const float*)d_in[1];
    float* out = (float*)d_out;

    const size_t NEED = 2ull * NCH * VOX * sizeof(_Float16) + 64;  // ~96 MB
    if (ws_size < NEED) {
        kdiag<<<1, 1, 0, stream>>>(out, (float)(ws_size >> 20));
        return;
    }

    _Float16* B0   = (_Float16*)d_ws;                  // 48 MB
    _Float16* B1   = B0 + (size_t)NCH * VOX;           // 48 MB
    float*    scal = (float*)(B1 + (size_t)NCH * VOX); // [2]=loss [3]=ticket

    f12 <<<dim3(NCH * DIM * 4, 2), 256, 0, stream>>>(y_true, y_pred, B0, scal);
    kmse<<<VOX / 4 / 256, 256, 0, stream>>>(B0, B1, scal, out);
}